// Round 14
// baseline (269.439 us; speedup 1.0000x reference)
//
#include <hip/hip_runtime.h>
#include <hip/hip_bf16.h>
#include <math.h>

// Causal attention, B=2 H=16 S=2048 D=64, fp32 in/out, bf16 MFMA compute.
// R21: 2x2 wave split (q-half x key-half). v19 totals: LDS pipe ~77% busy
// (8xb128 + 16xb64 + conflicts ~ 290cyc/wave-step; 4 waves each re-read the
// FULL K and V tile). Split keys too: wave (qh,kh) owns 32 q x 32 keys ->
// per-step LDS = 4xb128 + 8xb64 ~ 145cyc (2.6x cut), QK gate 4 reads, MFMA
// count unchanged (8 QK + 16 PV). Same 4 waves/256 threads/grid/staging/
// barriers/unroll-2/setprio as v19. Cost: O,l are key-half partials ->
// one swizzled-LDS reduction per block (reuses retired lk, conflict-free);
// diagonal tile idles 1/4 waves for one step. No cross-barrier reg banks
// (R20's spill trap). Gate: WRITE_SIZE must stay 16.4MB (spill = void).

constexpr int S  = 2048;
constexpr int D  = 64;
constexpr int BH = 32;                 // B*H
constexpr float SCALE = 0.125f;        // 64^-0.5
constexpr float LOG2E = 1.4426950408889634f;
constexpr float QPRE  = SCALE * LOG2E; // folded into Q before bf16 cvt

typedef __attribute__((ext_vector_type(8))) short bf16x8;   // K=32 A/B frag
typedef __attribute__((ext_vector_type(4))) short bf16x4;   // K=16 A/B frag
typedef __attribute__((ext_vector_type(4))) float f32x4;    // MFMA C/D frag

#if __has_builtin(__builtin_amdgcn_mfma_f32_16x16x16bf16_1k)
#define HAS_MFMA_1K 1
#else
#define HAS_MFMA_1K 0
#endif

#if __has_builtin(__builtin_amdgcn_exp2f)
#define EXP2F(x) __builtin_amdgcn_exp2f(x)
#else
#define EXP2F(x) exp2f(x)
#endif

__device__ __forceinline__ short f2bf(float x) {
    union { __hip_bfloat16 b; short s; } u; u.b = __float2bfloat16(x); return u.s;
}

// async global->LDS, 16B per lane; lds base wave-uniform, lanes land at +ln*16
__device__ __forceinline__ void gload_lds16(const void* g, void* lds) {
    __builtin_amdgcn_global_load_lds(
        (const __attribute__((address_space(1))) unsigned int*)g,
        (__attribute__((address_space(3))) unsigned int*)lds, 16, 0, 0);
}

// ---------------- pre-kernel: K fp32 -> bf16; V fp32 -> V^T bf16 ----------------
__global__ __launch_bounds__(256) void preconv_25993142075924(
    const float* __restrict__ Kg, const float* __restrict__ Vg,
    short* __restrict__ Kb, short* __restrict__ VT)
{
    const int kt = blockIdx.x, bh = blockIdx.y, tid = threadIdx.x;
    __shared__ float lt[64 * 65];              // [d][key] : lt[c*65 + r]
    const float* kp = Kg + (size_t)bh * S * D;
    const float* vp = Vg + (size_t)bh * S * D;
    short* kb = Kb + (size_t)bh * S * D;
    short* vt = VT + (size_t)bh * D * S;
    #pragma unroll
    for (int e = 0; e < 4; ++e) {
        int idx = (tid + e * 256) * 4;
        int r = idx >> 6, c = idx & 63;
        f32x4 k4 = *(const f32x4*)(kp + (size_t)(kt * 64 + r) * D + c);
        bf16x4 kb4;
        kb4[0] = f2bf(k4[0]); kb4[1] = f2bf(k4[1]);
        kb4[2] = f2bf(k4[2]); kb4[3] = f2bf(k4[3]);
        *(bf16x4*)(kb + (size_t)(kt * 64 + r) * D + c) = kb4;
        f32x4 v4 = *(const f32x4*)(vp + (size_t)(kt * 64 + r) * D + c);
        lt[(c + 0) * 65 + r] = v4[0];
        lt[(c + 1) * 65 + r] = v4[1];
        lt[(c + 2) * 65 + r] = v4[2];
        lt[(c + 3) * 65 + r] = v4[3];
    }
    __syncthreads();
    #pragma unroll
    for (int e = 0; e < 2; ++e) {
        int tt = tid + e * 256;
        int d  = tt >> 3;
        int j0 = (tt & 7) * 8;
        bf16x8 o;
        #pragma unroll
        for (int jj = 0; jj < 8; ++jj)
            o[jj] = f2bf(lt[d * 65 + j0 + jj]);
        *(bf16x8*)(vt + (size_t)d * S + kt * 64 + j0) = o;
    }
}

#if HAS_MFMA_1K
// ---------------- main kernel (v21): 2x2 q/key wave split ----------------
__global__ __launch_bounds__(256, 3) void attn_fwd_v21_25993142075924(
    const float* __restrict__ Qg, const short* __restrict__ Kb,
    const short* __restrict__ VT, float* __restrict__ Og)
{
    const int bh  = blockIdx.x;            // head 0..31 (x-major -> XCD locality)
    const int qb  = 31 - (int)blockIdx.y;  // q-block; y=0 -> qb=31 = longest
    const int tid = threadIdx.x;
    const int wv  = tid >> 6;              // wave 0..3
    const int ln  = tid & 63;
    const int c16 = ln & 15;
    const int qd  = ln >> 4;               // quad 0..3
    const int qh  = wv >> 1;               // q-half  (0: rows 0-31, 1: 32-63)
    const int kh  = wv & 1;                // key-half (0: keys 0-31, 1: 32-63)

    const int q0  = qb * 64 + qh * 32;     // wave's first q row
    const int nkt = qb + 1;                // causal tile count; diagonal at kt==qb

    // swizzled tiles: physical 16B-group gp at row r holds logical group gp^(r&7)
    __shared__ __align__(16) short lk[2][64 * 64];      // K tiles  [key][d]
    __shared__ __align__(16) short lv[2][64 * 64];      // V^T tiles [d][key]

    const float* qp = Qg + (size_t)bh * S * D;
    const short* kp = Kb + (size_t)bh * S * D;
    const short* vp = VT + (size_t)bh * D * S;
    float*       op = Og + (size_t)bh * S * D;

    // staging lane map: wave stages 16 K rows + 16 V^T rows per step (unchanged)
    const int srow0 = wv * 16 + (ln >> 3);
    const int sgrp0 = (ln & 7) ^ (srow0 & 7);
    const int srow1 = srow0 + 8;
    const int sgrp1 = (ln & 7) ^ (srow1 & 7);

    // ---- Q fragments for both q-groups of this wave's q-half ----
    bf16x8 qf[2][2];                       // [qg][khf]
    #pragma unroll
    for (int qg = 0; qg < 2; ++qg) {
        const float* src = qp + (size_t)(q0 + qg * 16 + c16) * D + qd * 8;
        #pragma unroll
        for (int khf = 0; khf < 2; ++khf) {
            f32x4 a = *(const f32x4*)(src + khf * 32);
            f32x4 b = *(const f32x4*)(src + khf * 32 + 4);
            bf16x8 f;
            f[0] = f2bf(a[0] * QPRE); f[1] = f2bf(a[1] * QPRE);
            f[2] = f2bf(a[2] * QPRE); f[3] = f2bf(a[3] * QPRE);
            f[4] = f2bf(b[0] * QPRE); f[5] = f2bf(b[1] * QPRE);
            f[6] = f2bf(b[2] * QPRE); f[7] = f2bf(b[3] * QPRE);
            qf[qg][khf] = f;
        }
    }

    // O^T key-half partials: oacc[qg][dt], col=q=c16 (of group qg), row=d
    f32x4 oacc[2][4] = {{{0,0,0,0},{0,0,0,0},{0,0,0,0},{0,0,0,0}},
                        {{0,0,0,0},{0,0,0,0},{0,0,0,0},{0,0,0,0}}};
    float lsum[2] = {0.f, 0.f};            // per-lane l partial (q = q0+qg*16+c16)

    // ---- prologue: stage tile 0 into buf 0 ----
    gload_lds16(kp + (size_t)srow0 * D + sgrp0 * 8, &lk[0][(wv * 16 + 0) * 64]);
    gload_lds16(vp + (size_t)srow0 * S + sgrp0 * 8, &lv[0][(wv * 16 + 0) * 64]);
    gload_lds16(kp + (size_t)srow1 * D + sgrp1 * 8, &lk[0][(wv * 16 + 8) * 64]);
    gload_lds16(vp + (size_t)srow1 * S + sgrp1 * 8, &lv[0][(wv * 16 + 8) * 64]);
    __syncthreads();

    // one K-tile step; cur is a LITERAL at each call site.
    auto step = [&](int kt_, int cur) __attribute__((always_inline)) {
        // ---- kf: this wave's 32 keys only -> 4 ds_read_b128 ----
        bf16x8 kf[2][2];                   // [nt][khf]
        #pragma unroll
        for (int nt = 0; nt < 2; ++nt) {
            const int row = kh * 32 + nt * 16 + c16;
            kf[nt][0] = *(const bf16x8*)&lk[cur][row * 64 + ((0 + qd) ^ (row & 7)) * 8];
            kf[nt][1] = *(const bf16x8*)&lk[cur][row * 64 + ((4 + qd) ^ (row & 7)) * 8];
        }

        // ---- staging DMA for next tile ----
        if (kt_ + 1 < nkt) {
            const int nxt = cur ^ 1;
            const size_t kb0 = (size_t)(kt_ + 1) * 64;
            gload_lds16(kp + (kb0 + srow0) * D + sgrp0 * 8, &lk[nxt][(wv * 16 + 0) * 64]);
            gload_lds16(vp + (size_t)srow0 * S + kb0 + sgrp0 * 8, &lv[nxt][(wv * 16 + 0) * 64]);
            gload_lds16(kp + (kb0 + srow1) * D + sgrp1 * 8, &lk[nxt][(wv * 16 + 8) * 64]);
            gload_lds16(vp + (size_t)srow1 * S + kb0 + sgrp1 * 8, &lv[nxt][(wv * 16 + 8) * 64]);
        }

        // ---- vf: V^T[all d][this wave's 32 keys] -> 8 ds_read_b64 ----
        bf16x4 vf[4][2];                   // [dt][nt]
        #pragma unroll
        for (int dt = 0; dt < 4; ++dt) {
            const int row = dt * 16 + c16;             // d row
            #pragma unroll
            for (int nt = 0; nt < 2; ++nt) {
                const int gl = kh * 4 + nt * 2 + (qd >> 1);
                const int gp = gl ^ (c16 & 7);
                vf[dt][nt] = *(const bf16x4*)&lv[cur][row * 64 + gp * 8 + (qd & 1) * 4];
            }
        }

        // ---- S^T = K*Q^T: t[qg][nt], D[m=key][n=q]: col=q=c16, row=qd*4+r ----
        float t[2][2][4];
        __builtin_amdgcn_s_setprio(1);
        #pragma unroll
        for (int qg = 0; qg < 2; ++qg) {
            #pragma unroll
            for (int nt = 0; nt < 2; ++nt) {
                f32x4 acc = {0,0,0,0};
                acc = __builtin_amdgcn_mfma_f32_16x16x32_bf16(kf[nt][0], qf[qg][0], acc, 0, 0, 0);
                acc = __builtin_amdgcn_mfma_f32_16x16x32_bf16(kf[nt][1], qf[qg][1], acc, 0, 0, 0);
                t[qg][nt][0] = acc[0]; t[qg][nt][1] = acc[1];
                t[qg][nt][2] = acc[2]; t[qg][nt][3] = acc[3];
            }
        }
        __builtin_amdgcn_s_setprio(0);

        if (kt_ == qb) {                   // diagonal tile: causal mask (key > q)
            #pragma unroll
            for (int qg = 0; qg < 2; ++qg)
                #pragma unroll
                for (int nt = 0; nt < 2; ++nt)
                    #pragma unroll
                    for (int r = 0; r < 4; ++r) {
                        int key = kt_ * 64 + kh * 32 + nt * 16 + qd * 4 + r;
                        if (key > q0 + qg * 16 + c16) t[qg][nt][r] = -INFINITY;
                    }
        }

        // ---- fused softmax + PV per (qg,nt) ----
        __builtin_amdgcn_s_setprio(1);
        #pragma unroll
        for (int qg = 0; qg < 2; ++qg) {
            #pragma unroll
            for (int nt = 0; nt < 2; ++nt) {
                float p0 = EXP2F(t[qg][nt][0]);
                float p1 = EXP2F(t[qg][nt][1]);
                float p2 = EXP2F(t[qg][nt][2]);
                float p3 = EXP2F(t[qg][nt][3]);
                lsum[qg] += (p0 + p1) + (p2 + p3);
                bf16x4 pf;
                pf[0] = f2bf(p0); pf[1] = f2bf(p1);
                pf[2] = f2bf(p2); pf[3] = f2bf(p3);
                #pragma unroll
                for (int dt = 0; dt < 4; ++dt)
                    oacc[qg][dt] = __builtin_amdgcn_mfma_f32_16x16x16bf16_1k(
                        vf[dt][nt], pf, oacc[qg][dt], 0, 0, 0);
            }
        }
        __builtin_amdgcn_s_setprio(0);

        __syncthreads();   // drains next-tile DMA; protects buffer reuse
    };

    // unrolled-by-2 main loop: cur is a literal in each copy
    int kt = 0;
    for (; kt + 1 < nkt; kt += 2) {
        step(kt, 0);
        step(kt + 1, 1);
    }
    if (kt < nkt) step(kt, 0);   // nkt odd: final step uses buf 0 (kt even)

    // ---- epilogue: cross-key-half reduction via retired lk/lv as scratch ----
    // lsum: reduce qd groups within wave first (q depends only on c16)
    lsum[0] += __shfl_xor(lsum[0], 16); lsum[0] += __shfl_xor(lsum[0], 32);
    lsum[1] += __shfl_xor(lsum[1], 16); lsum[1] += __shfl_xor(lsum[1], 32);

    float* scr  = (float*)&lk[0][0];       // 4096 floats: [qh][ln][32], swizzled
    float* scrl = (float*)&lv[0][0];       // 64 floats: [qh][qg][c16]
    const int sbase = (qh * 64 + ln) * 32;
    if (kh == 1) {
        #pragma unroll
        for (int c = 0; c < 8; ++c) {
            const int cc = c ^ (ln & 7);   // spread chunks across banks
            *(f32x4*)&scr[sbase + cc * 4] = oacc[c >> 2][c & 3];
        }
        if (qd == 0) {
            scrl[qh * 32 + c16]      = lsum[0];
            scrl[qh * 32 + 16 + c16] = lsum[1];
        }
    }
    __syncthreads();
    if (kh == 0) {
        #pragma unroll
        for (int c = 0; c < 8; ++c) {
            const int cc = c ^ (ln & 7);
            f32x4 p = *(const f32x4*)&scr[sbase + cc * 4];
            oacc[c >> 2][c & 3][0] += p[0];
            oacc[c >> 2][c & 3][1] += p[1];
            oacc[c >> 2][c & 3][2] += p[2];
            oacc[c >> 2][c & 3][3] += p[3];
        }
        const float inv0 = 1.0f / (lsum[0] + scrl[qh * 32 + c16]);
        const float inv1 = 1.0f / (lsum[1] + scrl[qh * 32 + 16 + c16]);
        #pragma unroll
        for (int qg = 0; qg < 2; ++qg) {
            const float inv = qg ? inv1 : inv0;
            float* dst = op + (size_t)(q0 + qg * 16 + c16) * D;
            #pragma unroll
            for (int dt = 0; dt < 4; ++dt) {
                f32x4 o;
                o[0] = oacc[qg][dt][0] * inv; o[1] = oacc[qg][dt][1] * inv;
                o[2] = oacc[qg][dt][2] * inv; o[3] = oacc[qg][dt][3] * inv;
                *(f32x4*)(dst + dt * 16 + qd * 4) = o;
            }
        }
    }
}
#endif  // HAS_MFMA_1K

// ---------------- fallback (fp32 inputs direct, LDS-staged, online softmax) ----------------
__global__ __launch_bounds__(256) void attn_fwd_v1_25993142075924(
    const float* __restrict__ Qg, const float* __restrict__ Kg,
    const float* __restrict__ Vg, float* __restrict__ Og)
{
    constexpr int KSTR = 72;
    constexpr int BQ = 64, BK = 64;
    const int qt  = blockIdx.x;
    const int bh  = blockIdx.y;
    const int tid = threadIdx.x;
    const int wv  = tid >> 6;
    const int ln  = tid & 63;
    const int c16 = ln & 15;
    const int qd  = ln >> 4;

    __shared__ __align__(16) __hip_bfloat16 lk [BK][KSTR];
    __shared__ __align__(16) __hip_bfloat16 lvt[D ][KSTR];
    __shared__ __align__(16) __hip_bfloat16 lp [4][16][KSTR];

    const size_t hoff = (size_t)bh * S * D;
    const float* qp = Qg + hoff;
    const float* kp = Kg + hoff;
    const float* vp = Vg + hoff;
    float*       op = Og + hoff;
    const int q0 = qt * BQ;

    bf16x8 qf[2];
    {
        const float* src = qp + (size_t)(q0 + wv*16 + c16) * D + qd*8;
        #pragma unroll
        for (int kh = 0; kh < 2; ++kh) {
            f32x4 a = *(const f32x4*)(src + kh*32);
            f32x4 b = *(const f32x4*)(src + kh*32 + 4);
            bf16x8 f;
            f[0]=f2bf(a[0]*QPRE); f[1]=f2bf(a[1]*QPRE); f[2]=f2bf(a[2]*QPRE); f[3]=f2bf(a[3]*QPRE);
            f[4]=f2bf(b[0]*QPRE); f[5]=f2bf(b[1]*QPRE); f[6]=f2bf(b[2]*QPRE); f[7]=f2bf(b[3]*QPRE);
            qf[kh] = f;
        }
    }

    f32x4 oacc[4] = {{0,0,0,0},{0,0,0,0},{0,0,0,0},{0,0,0,0}};
    float mrun[4] = {-INFINITY,-INFINITY,-INFINITY,-INFINITY};
    float lrun[4] = {0.f,0.f,0.f,0.f};

    const int nkt = qt + 1;
    for (int kt = 0; kt < nkt; ++kt) {
        __syncthreads();
        #pragma unroll
        for (int e = 0; e < 4; ++e) {
            int idx = (tid + e*256) * 4;
            int row = idx >> 6, col = idx & 63;
            f32x4 k4 = *(const f32x4*)(kp + (size_t)(kt*BK + row)*D + col);
            bf16x4 kb;
            kb[0]=f2bf(k4[0]); kb[1]=f2bf(k4[1]); kb[2]=f2bf(k4[2]); kb[3]=f2bf(k4[3]);
            *(bf16x4*)&lk[row][col] = kb;
            f32x4 v4 = *(const f32x4*)(vp + (size_t)(kt*BK + row)*D + col);
            lvt[col+0][row] = __float2bfloat16(v4[0]);
            lvt[col+1][row] = __float2bfloat16(v4[1]);
            lvt[col+2][row] = __float2bfloat16(v4[2]);
            lvt[col+3][row] = __float2bfloat16(v4[3]);
        }
        __syncthreads();

        float t[4][4];
        #pragma unroll
        for (int nt = 0; nt < 4; ++nt) {
            f32x4 acc = {0,0,0,0};
            #pragma unroll
            for (int kh = 0; kh < 2; ++kh) {
                bf16x8 kf = *(const bf16x8*)&lk[nt*16 + c16][kh*32 + qd*8];
                acc = __builtin_amdgcn_mfma_f32_16x16x32_bf16(qf[kh], kf, acc, 0, 0, 0);
            }
            #pragma unroll
            for (int r = 0; r < 4; ++r) t[nt][r] = acc[r];
        }
        if (kt == nkt - 1) {
            #pragma unroll
            for (int nt = 0; nt < 4; ++nt) {
                int j = kt*BK + nt*16 + c16;
                #pragma unroll
                for (int r = 0; r < 4; ++r)
                    if (j > q0 + wv*16 + qd*4 + r) t[nt][r] = -INFINITY;
            }
        }

        float pval[4][4];
        #pragma unroll
        for (int r = 0; r < 4; ++r) {
            float tm = fmaxf(fmaxf(t[0][r], t[1][r]), fmaxf(t[2][r], t[3][r]));
            tm = fmaxf(tm, __shfl_xor(tm, 1));
            tm = fmaxf(tm, __shfl_xor(tm, 2));
            tm = fmaxf(tm, __shfl_xor(tm, 4));
            tm = fmaxf(tm, __shfl_xor(tm, 8));
            float mnew  = fmaxf(mrun[r], tm);
            float alpha = exp2f(mrun[r] - mnew);
            mrun[r] = mnew;
            float rs = 0.f;
            #pragma unroll
            for (int nt = 0; nt < 4; ++nt) {
                float pv = exp2f(t[nt][r] - mnew);
                pval[nt][r] = pv;
                rs += pv;
            }
            rs += __shfl_xor(rs, 1);
            rs += __shfl_xor(rs, 2);
            rs += __shfl_xor(rs, 4);
            rs += __shfl_xor(rs, 8);
            lrun[r] = lrun[r] * alpha + rs;
            #pragma unroll
            for (int dt = 0; dt < 4; ++dt) oacc[dt][r] *= alpha;
        }

        #pragma unroll
        for (int nt = 0; nt < 4; ++nt)
            #pragma unroll
            for (int r = 0; r < 4; ++r)
                lp[wv][qd*4 + r][nt*16 + c16] = __float2bfloat16(pval[nt][r]);
        bf16x8 pf[2];
        #pragma unroll
        for (int kh = 0; kh < 2; ++kh)
            pf[kh] = *(const bf16x8*)&lp[wv][c16][kh*32 + qd*8];

        #pragma unroll
        for (int dt = 0; dt < 4; ++dt) {
            #pragma unroll
            for (int kh = 0; kh < 2; ++kh) {
                bf16x8 vf = *(const bf16x8*)&lvt[dt*16 + c16][kh*32 + qd*8];
                oacc[dt] = __builtin_amdgcn_mfma_f32_16x16x32_bf16(pf[kh], vf, oacc[dt], 0, 0, 0);
            }
        }
    }

    #pragma unroll
    for (int r = 0; r < 4; ++r) {
        float inv = 1.0f / lrun[r];
        float* dst = op + (size_t)(q0 + wv*16 + qd*4 + r) * D;
        #pragma unroll
        for (int dt = 0; dt < 4; ++dt)
            dst[dt*16 + c16] = oacc[dt][r] * inv;
    }
}

extern "C" void kernel_launch(void* const* d_in, const int* in_sizes, int n_in,
                              void* d_out, int out_size, void* d_ws, size_t ws_size,
                              hipStream_t stream) {
    const float* q = (const float*)d_in[0];
    const float* k = (const float*)d_in[1];
    const float* v = (const float*)d_in[2];
    float* out = (float*)d_out;
    const size_t elems = (size_t)BH * S * D;
    const size_t need  = 2 * elems * sizeof(short);   // Kb + VT, bf16
#if HAS_MFMA_1K
    if (ws_size >= need) {
        short* Kb = (short*)d_ws;
        short* VT = Kb + elems;
        preconv_25993142075924<<<dim3(S / 64, BH), 256, 0, stream>>>(k, v, Kb, VT);
        // grid: x = head (XCD affinity), y: y=0 -> qb=31 (longest first)
        attn_fwd_v21_25993142075924<<<dim3(BH, 32), 256, 0, stream>>>(q, Kb, VT, out);
        return;
    }
#endif
    (void)need;
    attn_fwd_v1_25993142075924<<<dim3(S / 64, BH), 256, 0, stream>>>(q, k, v, out);
}

// Round 15
// 131.684 us; speedup vs baseline: 2.0461x; 2.0461x over previous
//
#include <hip/hip_runtime.h>
#include <hip/hip_bf16.h>
#include <math.h>

// Causal attention, B=2 H=16 S=2048 D=64, fp32 in/out, bf16 MFMA compute.
// R22: DISCOVERY from R14 -- attn_fwd_v1 ran, proving HAS_MFMA_1K==0 on this
// toolchain: ALL session kernels (incl. the 41.8us champion v19) compiled the
// LDS-round-trip P + K=32 PV path. Real per-step LDS = 18xb128+4xb64 ~248cyc.
// This round: (a) 2x2 q/key wave split ported to the REAL path -- wave
// (qh,kh) owns 32q x 32keys: kf 4xb128, P-strip 4xb64 writes + 2xb128 reads,
// vf8 4xb128 => ~152cyc/step, same MFMA count, same 16 waves/CU; cross-kh
// reduction in retired lk (16KB scratch, double-barriered). (b) PV16
// detection chain: __builtin_amdgcn_mfma_f32_16x16x16_bf16 (gfx950-style
// name) -> _1k -> fallback. Launch NOT gated on it (R14's lesson).
// Gates: WRITE_SIZE must stay 16.4MB (spill=void); LDS_Block_Size tells
// which PV path compiled (32768 = PV16, 43008 = fallback).

constexpr int S  = 2048;
constexpr int D  = 64;
constexpr int BH = 32;                 // B*H
constexpr float SCALE = 0.125f;        // 64^-0.5
constexpr float LOG2E = 1.4426950408889634f;
constexpr float QPRE  = SCALE * LOG2E; // folded into Q before bf16 cvt
constexpr int PSTR2 = 40;              // P strip stride (shorts): 80B, 16B-aligned rows

typedef __attribute__((ext_vector_type(8))) short bf16x8;   // K=32 A/B frag
typedef __attribute__((ext_vector_type(4))) short bf16x4;   // K=16 A/B frag
typedef __attribute__((ext_vector_type(4))) float f32x4;    // MFMA C/D frag

#if __has_builtin(__builtin_amdgcn_mfma_f32_16x16x16_bf16)
#define MFMA_PV16(a, b, c) __builtin_amdgcn_mfma_f32_16x16x16_bf16(a, b, c, 0, 0, 0)
#define HAS_PV16 1
#elif __has_builtin(__builtin_amdgcn_mfma_f32_16x16x16bf16_1k)
#define MFMA_PV16(a, b, c) __builtin_amdgcn_mfma_f32_16x16x16bf16_1k(a, b, c, 0, 0, 0)
#define HAS_PV16 1
#else
#define HAS_PV16 0
#endif

#if __has_builtin(__builtin_amdgcn_exp2f)
#define EXP2F(x) __builtin_amdgcn_exp2f(x)
#else
#define EXP2F(x) exp2f(x)
#endif

__device__ __forceinline__ short f2bf(float x) {
    union { __hip_bfloat16 b; short s; } u; u.b = __float2bfloat16(x); return u.s;
}

// async global->LDS, 16B per lane; lds base wave-uniform, lanes land at +ln*16
__device__ __forceinline__ void gload_lds16(const void* g, void* lds) {
    __builtin_amdgcn_global_load_lds(
        (const __attribute__((address_space(1))) unsigned int*)g,
        (__attribute__((address_space(3))) unsigned int*)lds, 16, 0, 0);
}

// ---------------- pre-kernel: K fp32 -> bf16; V fp32 -> V^T bf16 ----------------
__global__ __launch_bounds__(256) void preconv_25993142075924(
    const float* __restrict__ Kg, const float* __restrict__ Vg,
    short* __restrict__ Kb, short* __restrict__ VT)
{
    const int kt = blockIdx.x, bh = blockIdx.y, tid = threadIdx.x;
    __shared__ float lt[64 * 65];              // [d][key] : lt[c*65 + r]
    const float* kp = Kg + (size_t)bh * S * D;
    const float* vp = Vg + (size_t)bh * S * D;
    short* kb = Kb + (size_t)bh * S * D;
    short* vt = VT + (size_t)bh * D * S;
    #pragma unroll
    for (int e = 0; e < 4; ++e) {
        int idx = (tid + e * 256) * 4;
        int r = idx >> 6, c = idx & 63;
        f32x4 k4 = *(const f32x4*)(kp + (size_t)(kt * 64 + r) * D + c);
        bf16x4 kb4;
        kb4[0] = f2bf(k4[0]); kb4[1] = f2bf(k4[1]);
        kb4[2] = f2bf(k4[2]); kb4[3] = f2bf(k4[3]);
        *(bf16x4*)(kb + (size_t)(kt * 64 + r) * D + c) = kb4;
        f32x4 v4 = *(const f32x4*)(vp + (size_t)(kt * 64 + r) * D + c);
        lt[(c + 0) * 65 + r] = v4[0];
        lt[(c + 1) * 65 + r] = v4[1];
        lt[(c + 2) * 65 + r] = v4[2];
        lt[(c + 3) * 65 + r] = v4[3];
    }
    __syncthreads();
    #pragma unroll
    for (int e = 0; e < 2; ++e) {
        int tt = tid + e * 256;
        int d  = tt >> 3;
        int j0 = (tt & 7) * 8;
        bf16x8 o;
        #pragma unroll
        for (int jj = 0; jj < 8; ++jj)
            o[jj] = f2bf(lt[d * 65 + j0 + jj]);
        *(bf16x8*)(vt + (size_t)d * S + kt * 64 + j0) = o;
    }
}

// ---------------- main kernel (v22): 2x2 q/key wave split, real PV path ----------------
__global__ __launch_bounds__(256, 3) void attn_fwd_v22_25993142075924(
    const float* __restrict__ Qg, const short* __restrict__ Kb,
    const short* __restrict__ VT, float* __restrict__ Og)
{
    const int bh  = blockIdx.x;            // head 0..31 (x-major -> XCD locality)
    const int qb  = 31 - (int)blockIdx.y;  // q-block; y=0 -> qb=31 = longest
    const int tid = threadIdx.x;
    const int wv  = tid >> 6;              // wave 0..3
    const int ln  = tid & 63;
    const int c16 = ln & 15;
    const int qd  = ln >> 4;               // quad 0..3
    const int qh  = wv >> 1;               // q-half  (0: rows 0-31, 1: 32-63)
    const int kh  = wv & 1;                // key-half (0: keys 0-31, 1: 32-63)

    const int q0  = qb * 64 + qh * 32;     // wave's first q row
    const int nkt = qb + 1;                // causal tile count; diagonal at kt==qb

    // swizzled tiles: physical 16B-group gp at row r holds logical group gp^(r&7)
    __shared__ __align__(16) short lk[2][64 * 64];      // K tiles  [key][d]
    __shared__ __align__(16) short lv[2][64 * 64];      // V^T tiles [d][key]
#if !HAS_PV16
    __shared__ __align__(16) short lp[4 * 32 * PSTR2];  // P strips: per wave 32q x 32keys
    short* lpw = lp + wv * 32 * PSTR2;
#endif

    const float* qp = Qg + (size_t)bh * S * D;
    const short* kp = Kb + (size_t)bh * S * D;
    const short* vp = VT + (size_t)bh * D * S;
    float*       op = Og + (size_t)bh * S * D;

    // staging lane map: wave stages 16 K rows + 16 V^T rows per step (unchanged)
    const int srow0 = wv * 16 + (ln >> 3);
    const int sgrp0 = (ln & 7) ^ (srow0 & 7);
    const int srow1 = srow0 + 8;
    const int sgrp1 = (ln & 7) ^ (srow1 & 7);

    // ---- Q fragments for both q-groups of this wave's q-half ----
    bf16x8 qf[2][2];                       // [qg][khf]
    #pragma unroll
    for (int qg = 0; qg < 2; ++qg) {
        const float* src = qp + (size_t)(q0 + qg * 16 + c16) * D + qd * 8;
        #pragma unroll
        for (int khf = 0; khf < 2; ++khf) {
            f32x4 a = *(const f32x4*)(src + khf * 32);
            f32x4 b = *(const f32x4*)(src + khf * 32 + 4);
            bf16x8 f;
            f[0] = f2bf(a[0] * QPRE); f[1] = f2bf(a[1] * QPRE);
            f[2] = f2bf(a[2] * QPRE); f[3] = f2bf(a[3] * QPRE);
            f[4] = f2bf(b[0] * QPRE); f[5] = f2bf(b[1] * QPRE);
            f[6] = f2bf(b[2] * QPRE); f[7] = f2bf(b[3] * QPRE);
            qf[qg][khf] = f;
        }
    }

    // O^T key-half partials: oacc[qg][dt], col=q=c16 (group qg), row=d=dt*16+qd*4+r
    f32x4 oacc[2][4] = {{{0,0,0,0},{0,0,0,0},{0,0,0,0},{0,0,0,0}},
                        {{0,0,0,0},{0,0,0,0},{0,0,0,0},{0,0,0,0}}};
    float lsum[2] = {0.f, 0.f};            // per-lane l partial (q = q0+qg*16+c16)

    // ---- prologue: stage tile 0 into buf 0 ----
    gload_lds16(kp + (size_t)srow0 * D + sgrp0 * 8, &lk[0][(wv * 16 + 0) * 64]);
    gload_lds16(vp + (size_t)srow0 * S + sgrp0 * 8, &lv[0][(wv * 16 + 0) * 64]);
    gload_lds16(kp + (size_t)srow1 * D + sgrp1 * 8, &lk[0][(wv * 16 + 8) * 64]);
    gload_lds16(vp + (size_t)srow1 * S + sgrp1 * 8, &lv[0][(wv * 16 + 8) * 64]);
    __syncthreads();

    // one K-tile step; cur is a LITERAL at each call site.
    auto step = [&](int kt_, int cur) __attribute__((always_inline)) {
        // ---- kf: this wave's 32 keys only -> 4 ds_read_b128 ----
        bf16x8 kf[2][2];                   // [nt][khf]
        #pragma unroll
        for (int nt = 0; nt < 2; ++nt) {
            const int row = kh * 32 + nt * 16 + c16;
            kf[nt][0] = *(const bf16x8*)&lk[cur][row * 64 + ((0 + qd) ^ (row & 7)) * 8];
            kf[nt][1] = *(const bf16x8*)&lk[cur][row * 64 + ((4 + qd) ^ (row & 7)) * 8];
        }

        // ---- staging DMA for next tile ----
        if (kt_ + 1 < nkt) {
            const int nxt = cur ^ 1;
            const size_t kb0 = (size_t)(kt_ + 1) * 64;
            gload_lds16(kp + (kb0 + srow0) * D + sgrp0 * 8, &lk[nxt][(wv * 16 + 0) * 64]);
            gload_lds16(vp + (size_t)srow0 * S + kb0 + sgrp0 * 8, &lv[nxt][(wv * 16 + 0) * 64]);
            gload_lds16(kp + (kb0 + srow1) * D + sgrp1 * 8, &lk[nxt][(wv * 16 + 8) * 64]);
            gload_lds16(vp + (size_t)srow1 * S + kb0 + sgrp1 * 8, &lv[nxt][(wv * 16 + 8) * 64]);
        }

#if HAS_PV16
        // ---- vf (K=16 PV): V^T[all d][this wave's 32 keys] -> 8 ds_read_b64 ----
        bf16x4 vf[4][2];                   // [dt][nt]
        #pragma unroll
        for (int dt = 0; dt < 4; ++dt) {
            const int row = dt * 16 + c16;             // d row
            #pragma unroll
            for (int nt = 0; nt < 2; ++nt) {
                const int gl = kh * 4 + nt * 2 + (qd >> 1);
                const int gp = gl ^ (c16 & 7);
                vf[dt][nt] = *(const bf16x4*)&lv[cur][row * 64 + gp * 8 + (qd & 1) * 4];
            }
        }
#endif

        // ---- S^T = K*Q^T: t[qg][nt], col=q=c16, row=key=kh*32+nt*16+qd*4+r ----
        float t[2][2][4];
        __builtin_amdgcn_s_setprio(1);
        #pragma unroll
        for (int qg = 0; qg < 2; ++qg) {
            #pragma unroll
            for (int nt = 0; nt < 2; ++nt) {
                f32x4 acc = {0,0,0,0};
                acc = __builtin_amdgcn_mfma_f32_16x16x32_bf16(kf[nt][0], qf[qg][0], acc, 0, 0, 0);
                acc = __builtin_amdgcn_mfma_f32_16x16x32_bf16(kf[nt][1], qf[qg][1], acc, 0, 0, 0);
                t[qg][nt][0] = acc[0]; t[qg][nt][1] = acc[1];
                t[qg][nt][2] = acc[2]; t[qg][nt][3] = acc[3];
            }
        }
        __builtin_amdgcn_s_setprio(0);

        if (kt_ == qb) {                   // diagonal tile: causal mask (key > q)
            #pragma unroll
            for (int qg = 0; qg < 2; ++qg)
                #pragma unroll
                for (int nt = 0; nt < 2; ++nt)
                    #pragma unroll
                    for (int r = 0; r < 4; ++r) {
                        int key = kt_ * 64 + kh * 32 + nt * 16 + qd * 4 + r;
                        if (key > q0 + qg * 16 + c16) t[qg][nt][r] = -INFINITY;
                    }
        }

#if HAS_PV16
        // ---- fused softmax + K=16 PV, in-register P ----
        __builtin_amdgcn_s_setprio(1);
        #pragma unroll
        for (int qg = 0; qg < 2; ++qg) {
            #pragma unroll
            for (int nt = 0; nt < 2; ++nt) {
                float p0 = EXP2F(t[qg][nt][0]);
                float p1 = EXP2F(t[qg][nt][1]);
                float p2 = EXP2F(t[qg][nt][2]);
                float p3 = EXP2F(t[qg][nt][3]);
                lsum[qg] += (p0 + p1) + (p2 + p3);
                bf16x4 pf;
                pf[0] = f2bf(p0); pf[1] = f2bf(p1);
                pf[2] = f2bf(p2); pf[3] = f2bf(p3);
                #pragma unroll
                for (int dt = 0; dt < 4; ++dt)
                    oacc[qg][dt] = MFMA_PV16(vf[dt][nt], pf, oacc[qg][dt]);
            }
        }
        __builtin_amdgcn_s_setprio(0);
#else
        // ---- softmax -> wave-private P strip (4x b64 writes) -> K=32 PV ----
        #pragma unroll
        for (int qg = 0; qg < 2; ++qg) {
            #pragma unroll
            for (int nt = 0; nt < 2; ++nt) {
                bf16x4 pw;
                #pragma unroll
                for (int r = 0; r < 4; ++r) {
                    float pv = EXP2F(t[qg][nt][r]);
                    lsum[qg] += pv;
                    pw[r] = f2bf(pv);
                }
                // key-local index nt*16+qd*4 within [0,32); row qg*16+c16
                *(bf16x4*)&lpw[(qg * 16 + c16) * PSTR2 + nt * 16 + qd * 4] = pw;
            }
        }
        // P^T B-frags: lane needs keys qd*8..qd*8+7 of its q row (16B read)
        bf16x8 pf2[2];
        #pragma unroll
        for (int qg = 0; qg < 2; ++qg)
            pf2[qg] = *(const bf16x8*)&lpw[(qg * 16 + c16) * PSTR2 + qd * 8];
        // V^T A-frags over the wave's 32 keys: 4x ds_read_b128
        __builtin_amdgcn_s_setprio(1);
        #pragma unroll
        for (int dt = 0; dt < 4; ++dt) {
            const int row = dt * 16 + c16;
            const int gp  = (kh * 4 + qd) ^ (row & 7);
            bf16x8 vf8 = *(const bf16x8*)&lv[cur][row * 64 + gp * 8];
            #pragma unroll
            for (int qg = 0; qg < 2; ++qg)
                oacc[qg][dt] = __builtin_amdgcn_mfma_f32_16x16x32_bf16(
                    vf8, pf2[qg], oacc[qg][dt], 0, 0, 0);
        }
        __builtin_amdgcn_s_setprio(0);
#endif

        __syncthreads();   // drains next-tile DMA; protects buffer reuse
    };

    // unrolled-by-2 main loop: cur is a literal in each copy
    int kt = 0;
    for (; kt + 1 < nkt; kt += 2) {
        step(kt, 0);
        step(kt + 1, 1);
    }
    if (kt < nkt) step(kt, 0);   // nkt odd: final step uses buf 0 (kt even)

    // ---- epilogue: cross-key-half reduction via retired lk/lv as scratch ----
    lsum[0] += __shfl_xor(lsum[0], 16); lsum[0] += __shfl_xor(lsum[0], 32);
    lsum[1] += __shfl_xor(lsum[1], 16); lsum[1] += __shfl_xor(lsum[1], 32);

    float* scr  = (float*)&lk[0][0];       // 4096 floats = 16KB (both lk bufs)
    float* scrl = (float*)&lv[0][0];       // 64 floats
    const int sbase = (qh * 64 + ln) * 32;
    if (kh == 1) {
        #pragma unroll
        for (int c = 0; c < 8; ++c) {
            const int cc = c ^ (ln & 7);   // spread chunks across banks
            *(f32x4*)&scr[sbase + cc * 4] = oacc[c >> 2][c & 3];
        }
        if (qd == 0) {
            scrl[qh * 32 + c16]      = lsum[0];
            scrl[qh * 32 + 16 + c16] = lsum[1];
        }
    }
    __syncthreads();
    if (kh == 0) {
        #pragma unroll
        for (int c = 0; c < 8; ++c) {
            const int cc = c ^ (ln & 7);
            f32x4 p = *(const f32x4*)&scr[sbase + cc * 4];
            oacc[c >> 2][c & 3][0] += p[0];
            oacc[c >> 2][c & 3][1] += p[1];
            oacc[c >> 2][c & 3][2] += p[2];
            oacc[c >> 2][c & 3][3] += p[3];
        }
        const float inv0 = 1.0f / (lsum[0] + scrl[qh * 32 + c16]);
        const float inv1 = 1.0f / (lsum[1] + scrl[qh * 32 + 16 + c16]);
        #pragma unroll
        for (int qg = 0; qg < 2; ++qg) {
            const float inv = qg ? inv1 : inv0;
            float* dst = op + (size_t)(q0 + qg * 16 + c16) * D;
            #pragma unroll
            for (int dt = 0; dt < 4; ++dt) {
                f32x4 o;
                o[0] = oacc[qg][dt][0] * inv; o[1] = oacc[qg][dt][1] * inv;
                o[2] = oacc[qg][dt][2] * inv; o[3] = oacc[qg][dt][3] * inv;
                *(f32x4*)(dst + dt * 16 + qd * 4) = o;
            }
        }
    }
}

// ---------------- fallback (fp32 inputs direct, LDS-staged, online softmax) ----------------
__global__ __launch_bounds__(256) void attn_fwd_v1_25993142075924(
    const float* __restrict__ Qg, const float* __restrict__ Kg,
    const float* __restrict__ Vg, float* __restrict__ Og)
{
    constexpr int KSTR = 72;
    constexpr int BQ = 64, BK = 64;
    const int qt  = blockIdx.x;
    const int bh  = blockIdx.y;
    const int tid = threadIdx.x;
    const int wv  = tid >> 6;
    const int ln  = tid & 63;
    const int c16 = ln & 15;
    const int qd  = ln >> 4;

    __shared__ __align__(16) __hip_bfloat16 lk [BK][KSTR];
    __shared__ __align__(16) __hip_bfloat16 lvt[D ][KSTR];
    __shared__ __align__(16) __hip_bfloat16 lp [4][16][KSTR];

    const size_t hoff = (size_t)bh * S * D;
    const float* qp = Qg + hoff;
    const float* kp = Kg + hoff;
    const float* vp = Vg + hoff;
    float*       op = Og + hoff;
    const int q0 = qt * BQ;

    bf16x8 qf[2];
    {
        const float* src = qp + (size_t)(q0 + wv*16 + c16) * D + qd*8;
        #pragma unroll
        for (int kh = 0; kh < 2; ++kh) {
            f32x4 a = *(const f32x4*)(src + kh*32);
            f32x4 b = *(const f32x4*)(src + kh*32 + 4);
            bf16x8 f;
            f[0]=f2bf(a[0]*QPRE); f[1]=f2bf(a[1]*QPRE); f[2]=f2bf(a[2]*QPRE); f[3]=f2bf(a[3]*QPRE);
            f[4]=f2bf(b[0]*QPRE); f[5]=f2bf(b[1]*QPRE); f[6]=f2bf(b[2]*QPRE); f[7]=f2bf(b[3]*QPRE);
            qf[kh] = f;
        }
    }

    f32x4 oacc[4] = {{0,0,0,0},{0,0,0,0},{0,0,0,0},{0,0,0,0}};
    float mrun[4] = {-INFINITY,-INFINITY,-INFINITY,-INFINITY};
    float lrun[4] = {0.f,0.f,0.f,0.f};

    const int nkt = qt + 1;
    for (int kt = 0; kt < nkt; ++kt) {
        __syncthreads();
        #pragma unroll
        for (int e = 0; e < 4; ++e) {
            int idx = (tid + e*256) * 4;
            int row = idx >> 6, col = idx & 63;
            f32x4 k4 = *(const f32x4*)(kp + (size_t)(kt*BK + row)*D + col);
            bf16x4 kb;
            kb[0]=f2bf(k4[0]); kb[1]=f2bf(k4[1]); kb[2]=f2bf(k4[2]); kb[3]=f2bf(k4[3]);
            *(bf16x4*)&lk[row][col] = kb;
            f32x4 v4 = *(const f32x4*)(vp + (size_t)(kt*BK + row)*D + col);
            lvt[col+0][row] = __float2bfloat16(v4[0]);
            lvt[col+1][row] = __float2bfloat16(v4[1]);
            lvt[col+2][row] = __float2bfloat16(v4[2]);
            lvt[col+3][row] = __float2bfloat16(v4[3]);
        }
        __syncthreads();

        float t[4][4];
        #pragma unroll
        for (int nt = 0; nt < 4; ++nt) {
            f32x4 acc = {0,0,0,0};
            #pragma unroll
            for (int kh = 0; kh < 2; ++kh) {
                bf16x8 kf = *(const bf16x8*)&lk[nt*16 + c16][kh*32 + qd*8];
                acc = __builtin_amdgcn_mfma_f32_16x16x32_bf16(qf[kh], kf, acc, 0, 0, 0);
            }
            #pragma unroll
            for (int r = 0; r < 4; ++r) t[nt][r] = acc[r];
        }
        if (kt == nkt - 1) {
            #pragma unroll
            for (int nt = 0; nt < 4; ++nt) {
                int j = kt*BK + nt*16 + c16;
                #pragma unroll
                for (int r = 0; r < 4; ++r)
                    if (j > q0 + wv*16 + qd*4 + r) t[nt][r] = -INFINITY;
            }
        }

        float pval[4][4];
        #pragma unroll
        for (int r = 0; r < 4; ++r) {
            float tm = fmaxf(fmaxf(t[0][r], t[1][r]), fmaxf(t[2][r], t[3][r]));
            tm = fmaxf(tm, __shfl_xor(tm, 1));
            tm = fmaxf(tm, __shfl_xor(tm, 2));
            tm = fmaxf(tm, __shfl_xor(tm, 4));
            tm = fmaxf(tm, __shfl_xor(tm, 8));
            float mnew  = fmaxf(mrun[r], tm);
            float alpha = exp2f(mrun[r] - mnew);
            mrun[r] = mnew;
            float rs = 0.f;
            #pragma unroll
            for (int nt = 0; nt < 4; ++nt) {
                float pv = exp2f(t[nt][r] - mnew);
                pval[nt][r] = pv;
                rs += pv;
            }
            rs += __shfl_xor(rs, 1);
            rs += __shfl_xor(rs, 2);
            rs += __shfl_xor(rs, 4);
            rs += __shfl_xor(rs, 8);
            lrun[r] = lrun[r] * alpha + rs;
            #pragma unroll
            for (int dt = 0; dt < 4; ++dt) oacc[dt][r] *= alpha;
        }

        #pragma unroll
        for (int nt = 0; nt < 4; ++nt)
            #pragma unroll
            for (int r = 0; r < 4; ++r)
                lp[wv][qd*4 + r][nt*16 + c16] = __float2bfloat16(pval[nt][r]);
        bf16x8 pf[2];
        #pragma unroll
        for (int kh = 0; kh < 2; ++kh)
            pf[kh] = *(const bf16x8*)&lp[wv][c16][kh*32 + qd*8];

        #pragma unroll
        for (int dt = 0; dt < 4; ++dt) {
            #pragma unroll
            for (int kh = 0; kh < 2; ++kh) {
                bf16x8 vf = *(const bf16x8*)&lvt[dt*16 + c16][kh*32 + qd*8];
                oacc[dt] = __builtin_amdgcn_mfma_f32_16x16x32_bf16(pf[kh], vf, oacc[dt], 0, 0, 0);
            }
        }
    }

    #pragma unroll
    for (int r = 0; r < 4; ++r) {
        float inv = 1.0f / lrun[r];
        float* dst = op + (size_t)(q0 + wv*16 + qd*4 + r) * D;
        #pragma unroll
        for (int dt = 0; dt < 4; ++dt)
            dst[dt*16 + c16] = oacc[dt][r] * inv;
    }
}

extern "C" void kernel_launch(void* const* d_in, const int* in_sizes, int n_in,
                              void* d_out, int out_size, void* d_ws, size_t ws_size,
                              hipStream_t stream) {
    const float* q = (const float*)d_in[0];
    const float* k = (const float*)d_in[1];
    const float* v = (const float*)d_in[2];
    float* out = (float*)d_out;
    const size_t elems = (size_t)BH * S * D;
    const size_t need  = 2 * elems * sizeof(short);   // Kb + VT, bf16
    if (ws_size >= need) {
        short* Kb = (short*)d_ws;
        short* VT = Kb + elems;
        preconv_25993142075924<<<dim3(S / 64, BH), 256, 0, stream>>>(k, v, Kb, VT);
        // grid: x = head (XCD affinity), y: y=0 -> qb=31 (longest first)
        attn_fwd_v22_25993142075924<<<dim3(BH, 32), 256, 0, stream>>>(q, Kb, VT, out);
    } else {
        attn_fwd_v1_25993142075924<<<dim3(S / 64, BH), 256, 0, stream>>>(q, k, v, out);
    }
}